// Round 4
// baseline (8690.470 us; speedup 1.0000x reference)
//
#include <hip/hip_runtime.h>
#include <math.h>

#define SD 7
#define HID 64
#define NQ 16      // HID/4
#define NITER 10

typedef float f4 __attribute__((ext_vector_type(4)));
typedef float f2 __attribute__((ext_vector_type(2)));

#define REP16(M) M(0) M(1) M(2) M(3) M(4) M(5) M(6) M(7) M(8) M(9) M(10) M(11) M(12) M(13) M(14) M(15)
#define REP15(M) M(1) M(2) M(3) M(4) M(5) M(6) M(7) M(8) M(9) M(10) M(11) M(12) M(13) M(14) M(15)
#define REP7(M)  M(0) M(1) M(2) M(3) M(4) M(5) M(6)

__device__ __forceinline__ f4 splat4(float s) { return (f4){s, s, s, s}; }
__device__ __forceinline__ f4 vfma4(f4 a, f4 b, f4 c) { return __builtin_elementwise_fma(a, b, c); }
__device__ __forceinline__ f2 vfma2(f2 a, f2 b, f2 c) { return __builtin_elementwise_fma(a, b, c); }

__global__ __launch_bounds__(256) __attribute__((amdgpu_waves_per_eu(1, 2)))
void strange_loop_kernel(const float* __restrict__ s7,
                         const float* __restrict__ w0,
                         const float* __restrict__ b0,
                         const float* __restrict__ lns,
                         const float* __restrict__ lnb,
                         const float* __restrict__ ow,
                         const float* __restrict__ ob,
                         float* __restrict__ out_mu,
                         float* __restrict__ out_cv,
                         int Bn)
{
    // ---- weights in LDS: uniform-address broadcast reads, imm offsets ----
    __shared__ float w0s[14 * HID];   // [14][64]
    __shared__ float ows[HID * 8];    // [64][8] (7 real + 1 zero pad)
    __shared__ float lnss[HID];
    __shared__ float lnbs[HID];
    __shared__ float obs[8];

    const int tid = threadIdx.x;
    for (int i = tid; i < 14 * HID; i += 256) w0s[i] = w0[i];
    for (int i = tid; i < HID * SD; i += 256) ows[(i / SD) * 8 + (i % SD)] = ow[i];
    if (tid < HID) { lnss[tid] = lns[tid]; lnbs[tid] = lnb[tid]; ows[tid * 8 + 7] = 0.0f; }
    if (tid < 8) obs[tid] = (tid < SD) ? ob[tid] : 0.0f;
    __syncthreads();

    const f4* __restrict__ w0sv  = (const f4*)w0s;   // [14][NQ]
    const f2* __restrict__ owsv  = (const f2*)ows;   // [64][4]
    const f4* __restrict__ lnsv4 = (const f4*)lnss;  // [NQ]
    const f4* __restrict__ lnbv4 = (const f4*)lnbs;  // [NQ]
    const f2* __restrict__ obsv  = (const f2*)obs;   // [4]

    int row = blockIdx.x * blockDim.x + tid;
    if (row >= Bn) row = Bn - 1;   // clamp: uniform control flow, dup write benign

    float s[SD];
#define LD_S(k) s[k] = s7[(size_t)row * SD + (k)];
    REP7(LD_S)

    const f4* __restrict__ b0v = (const f4*)b0;

    // iteration-invariant: B[q] = b0 + sum_k s[k] * W0[7+k][.]
    f4 Bv[NQ];
    {
        f4 c0 = splat4(s[0]), c1 = splat4(s[1]), c2 = splat4(s[2]), c3 = splat4(s[3]);
        f4 c4 = splat4(s[4]), c5 = splat4(s[5]), c6 = splat4(s[6]);
#define INITB(q) { f4 a = b0v[q]; \
        a = vfma4(c0, w0sv[(SD + 0) * NQ + (q)], a); \
        a = vfma4(c1, w0sv[(SD + 1) * NQ + (q)], a); \
        a = vfma4(c2, w0sv[(SD + 2) * NQ + (q)], a); \
        a = vfma4(c3, w0sv[(SD + 3) * NQ + (q)], a); \
        a = vfma4(c4, w0sv[(SD + 4) * NQ + (q)], a); \
        a = vfma4(c5, w0sv[(SD + 5) * NQ + (q)], a); \
        a = vfma4(c6, w0sv[(SD + 6) * NQ + (q)], a); \
        Bv[q] = a; }
        REP16(INITB)
    }

    float mu[SD];
#define INITMU(i) mu[i] = 0.37796447300922720f;   // 1/sqrt(7)
    REP7(INITMU)
    float conv = 0.0f;

#pragma unroll 1
    for (int it = 0; it < NITER; ++it) {
        // ---- fc0: x = B + sum_k mu[k]*W0[k][.] ----
        f4 x[NQ];
        {
            f4 m0 = splat4(mu[0]), m1 = splat4(mu[1]), m2 = splat4(mu[2]), m3 = splat4(mu[3]);
            f4 m4 = splat4(mu[4]), m5 = splat4(mu[5]), m6 = splat4(mu[6]);
#define FC0(q) { f4 a = vfma4(m0, w0sv[0 * NQ + (q)], Bv[q]); \
            a = vfma4(m1, w0sv[1 * NQ + (q)], a); \
            a = vfma4(m2, w0sv[2 * NQ + (q)], a); \
            a = vfma4(m3, w0sv[3 * NQ + (q)], a); \
            a = vfma4(m4, w0sv[4 * NQ + (q)], a); \
            a = vfma4(m5, w0sv[5 * NQ + (q)], a); \
            a = vfma4(m6, w0sv[6 * NQ + (q)], a); \
            x[q] = a; }
            REP16(FC0)
        }

        // ---- LayerNorm (two-pass, striped partials, same order as before) ----
        f4 sacc = x[0];
#define SAC(q) sacc += x[q];
        REP15(SAC)
        float mean = ((sacc.x + sacc.y) + (sacc.z + sacc.w)) * (1.0f / HID);

        f4 vacc = {0.f, 0.f, 0.f, 0.f};
        {
            f4 mn4 = splat4(mean);
#define VAC(q) { f4 a = x[q] - mn4; vacc = vfma4(a, a, vacc); x[q] = a; }
            REP16(VAC)
        }
        float var  = ((vacc.x + vacc.y) + (vacc.z + vacc.w)) * (1.0f / HID);
        float rstd = 1.0f / sqrtf(var + 1e-6f);

        // ---- scale/shift + GELU (per-element ops identical to passing kernel) ----
        {
            f4 rs4 = splat4(rstd);
            const f4 kB4 = splat4(0.044715f);
            const f4 kC4 = splat4(-1.5957691216057308f);   // -2*sqrt(2/pi)
            const f4 one4 = splat4(1.0f);
#define GEL(q) { f4 g = vfma4(x[q] * rs4, lnsv4[q], lnbv4[q]); \
            f4 g2 = g * g; f4 g3 = g2 * g; \
            f4 z  = kC4 * vfma4(kB4, g3, g); \
            f4 e; e.x = __expf(z.x); e.y = __expf(z.y); e.z = __expf(z.z); e.w = __expf(z.w); \
            f4 den = one4 + e; \
            f4 r; r.x = __fdividef(g.x, den.x); r.y = __fdividef(g.y, den.y); \
            r.z = __fdividef(g.z, den.z); r.w = __fdividef(g.w, den.w); \
            x[q] = r; }
            REP16(GEL)
        }

        // ---- out matmul [1x64]x[64x7], packed over i, j ascending ----
        f2 u01, u23, u45, u6d;
        {
            f2 xx = (f2){x[0].x, x[0].x};
            u01 = vfma2(xx, owsv[0], obsv[0]);
            u23 = vfma2(xx, owsv[1], obsv[1]);
            u45 = vfma2(xx, owsv[2], obsv[2]);
            u6d = vfma2(xx, owsv[3], obsv[3]);
        }
#define OUT1(j, xj) { f2 xx = (f2){(xj), (xj)}; \
        u01 = vfma2(xx, owsv[(j) * 4 + 0], u01); \
        u23 = vfma2(xx, owsv[(j) * 4 + 1], u23); \
        u45 = vfma2(xx, owsv[(j) * 4 + 2], u45); \
        u6d = vfma2(xx, owsv[(j) * 4 + 3], u6d); }
#define OUTQ(q) { if ((q) != 0) OUT1(4*(q)+0, x[q].x) \
        OUT1(4*(q)+1, x[q].y) \
        OUT1(4*(q)+2, x[q].z) \
        OUT1(4*(q)+3, x[q].w) }
        REP16(OUTQ)

        float u[SD];
        u[0] = u01.x; u[1] = u01.y; u[2] = u23.x; u[3] = u23.y;
        u[4] = u45.x; u[5] = u45.y; u[6] = u6d.x;

        // ---- L2 normalize ----
        float ss = 0.f;
#define SSQ(i) ss = fmaf(u[i], u[i], ss);
        REP7(SSQ)
        float inv = __fdividef(1.0f, sqrtf(ss) + 1e-8f);

        // ---- damped update + convergence ----
        float dd = 0.f;
#define UPD(i) { float un = u[i] * inv; float mn = 0.5f * mu[i] + 0.5f * un; \
        float d = mn - mu[i]; dd = fmaf(d, d, dd); mu[i] = mn; }
        REP7(UPD)
        if (sqrtf(dd) < 1e-4f) conv = 1.0f;
    }

#define ST(i) out_mu[(size_t)row * SD + (i)] = mu[i];
    REP7(ST)
    out_cv[row] = conv;
}

extern "C" void kernel_launch(void* const* d_in, const int* in_sizes, int n_in,
                              void* d_out, int out_size, void* d_ws, size_t ws_size,
                              hipStream_t stream) {
    const float* s7  = (const float*)d_in[0];
    const float* w0  = (const float*)d_in[1];
    const float* b0  = (const float*)d_in[2];
    const float* lns = (const float*)d_in[3];
    const float* lnb = (const float*)d_in[4];
    const float* ow  = (const float*)d_in[5];
    const float* ob  = (const float*)d_in[6];
    const int Bn = in_sizes[0] / SD;

    float* out_mu = (float*)d_out;
    float* out_cv = out_mu + (size_t)Bn * SD;

    const int block = 256;
    const int grid  = (Bn + block - 1) / block;
    hipLaunchKernelGGL(strange_loop_kernel, dim3(grid), dim3(block), 0, stream,
                       s7, w0, b0, lns, lnb, ow, ob, out_mu, out_cv, Bn);
}

// Round 5
// 756.175 us; speedup vs baseline: 11.4927x; 11.4927x over previous
//
#include <hip/hip_runtime.h>
#include <math.h>

#define SD 7
#define HID 64
#define NITER 10

typedef float f16s __attribute__((ext_vector_type(16)));
typedef float f8s  __attribute__((ext_vector_type(8)));

#define REP4(M)  M(0) M(1) M(2) M(3)
#define REP7(M)  M(0) M(1) M(2) M(3) M(4) M(5) M(6)
#define REP15(M) M(1) M(2) M(3) M(4) M(5) M(6) M(7) M(8) M(9) M(10) M(11) M(12) M(13) M(14) M(15)
#define REP16(M) M(0) M(1) M(2) M(3) M(4) M(5) M(6) M(7) M(8) M(9) M(10) M(11) M(12) M(13) M(14) M(15)
#define AP16(M, ...) M(0, __VA_ARGS__) M(1, __VA_ARGS__) M(2, __VA_ARGS__) M(3, __VA_ARGS__) \
    M(4, __VA_ARGS__) M(5, __VA_ARGS__) M(6, __VA_ARGS__) M(7, __VA_ARGS__) \
    M(8, __VA_ARGS__) M(9, __VA_ARGS__) M(10, __VA_ARGS__) M(11, __VA_ARGS__) \
    M(12, __VA_ARGS__) M(13, __VA_ARGS__) M(14, __VA_ARGS__) M(15, __VA_ARGS__)

// 64 uniform floats -> SGPRs via scalar cache. volatile => never hoisted/CSE'd.
#define SLOAD4(d0, d1, d2, d3, p, o0, o1, o2, o3) \
    asm volatile("s_load_dwordx16 %0, %4, %5\n\t" \
                 "s_load_dwordx16 %1, %4, %6\n\t" \
                 "s_load_dwordx16 %2, %4, %7\n\t" \
                 "s_load_dwordx16 %3, %4, %8\n\t" \
                 "s_waitcnt lgkmcnt(0)" \
                 : "=&s"(d0), "=&s"(d1), "=&s"(d2), "=&s"(d3) \
                 : "s"(p), "i"(o0), "i"(o1), "i"(o2), "i"(o3));

#define SLOAD2P(d0, d1, pa, pb, oa, ob_) \
    asm volatile("s_load_dwordx16 %0, %2, %4\n\t" \
                 "s_load_dwordx16 %1, %3, %5\n\t" \
                 "s_waitcnt lgkmcnt(0)" \
                 : "=&s"(d0), "=&s"(d1) \
                 : "s"(pa), "s"(pb), "i"(oa), "i"(ob_));

#define SLOADX8(d0, p) \
    asm volatile("s_load_dwordx8 %0, %1, 0\n\t" \
                 "s_waitcnt lgkmcnt(0)" \
                 : "=&s"(d0) : "s"(p));

// one fma row element: arr[base+e] = fma(m, W[e], arr[base+e])
#define FMAE(e, arr, base, m, W) (arr)[(base)+(e)] = fmaf((m), (W)[(e)], (arr)[(base)+(e)]);
#define FMAROW(arr, m, wa, wb, wc, wd) \
    AP16(FMAE, arr, 0,  m, wa) AP16(FMAE, arr, 16, m, wb) \
    AP16(FMAE, arr, 32, m, wc) AP16(FMAE, arr, 48, m, wd)

__global__ __launch_bounds__(256) __attribute__((amdgpu_waves_per_eu(2)))
void strange_loop_kernel(const float* __restrict__ s7,
                         const float* __restrict__ w0,
                         const float* __restrict__ b0,
                         const float* __restrict__ lns,
                         const float* __restrict__ lnb,
                         const float* __restrict__ ow,
                         const float* __restrict__ ob,
                         float* __restrict__ out_mu,
                         float* __restrict__ out_cv,
                         int Bn)
{
    int row = blockIdx.x * blockDim.x + threadIdx.x;
    if (row >= Bn) row = Bn - 1;   // clamp: uniform control flow, dup write benign

    float s[SD];
#define LD_S(k) s[k] = s7[(size_t)row * SD + (k)];
    REP7(LD_S)

    // ---- iteration-invariant: Be[j] = b0[j] + sum_k s[k]*W0[7+k][j] ----
    float Be[HID];
    {
        f16s ba, bb, bc, bd;
        SLOAD4(ba, bb, bc, bd, b0, 0, 64, 128, 192)
#define B0E(e, base, W) Be[(base)+(e)] = (W)[(e)];
        AP16(B0E, 0, ba) AP16(B0E, 16, bb) AP16(B0E, 32, bc) AP16(B0E, 48, bd)
    }
#define BIK(k) { f16s wa, wb, wc, wd; \
    SLOAD4(wa, wb, wc, wd, w0, (7+(k))*256, (7+(k))*256+64, (7+(k))*256+128, (7+(k))*256+192) \
    const float sk = s[k]; \
    FMAROW(Be, sk, wa, wb, wc, wd) }
    REP7(BIK)

    f8s obv;
    SLOADX8(obv, ob)

    float mu[SD];
#define INITMU(i) mu[i] = 0.37796447300922720f;   // 1/sqrt(7)
    REP7(INITMU)
    float conv = 0.0f;

#pragma unroll 1
    for (int it = 0; it < NITER; ++it) {
        // ---- fc0: xe = Be + sum_k mu[k]*W0[k][.] ----
        float xe[HID];
#define CPE(e, base) xe[(base)+(e)] = Be[(base)+(e)];
        AP16(CPE, 0) AP16(CPE, 16) AP16(CPE, 32) AP16(CPE, 48)
#define FC0K(k) { f16s wa, wb, wc, wd; \
        SLOAD4(wa, wb, wc, wd, w0, (k)*256, (k)*256+64, (k)*256+128, (k)*256+192) \
        const float mk = mu[k]; \
        FMAROW(xe, mk, wa, wb, wc, wd) }
        REP7(FC0K)

        // ---- LayerNorm (two-pass, striped partials: same order as passing kernel) ----
        float p0 = xe[0], p1 = xe[1], p2 = xe[2], p3 = xe[3];
#define SACE(q) p0 += xe[4*(q)+0]; p1 += xe[4*(q)+1]; p2 += xe[4*(q)+2]; p3 += xe[4*(q)+3];
        REP15(SACE)
        float mean = ((p0 + p1) + (p2 + p3)) * (1.0f / HID);

        float v0 = 0.f, v1 = 0.f, v2 = 0.f, v3 = 0.f;
#define VACE(q) { float a0 = xe[4*(q)+0] - mean, a1 = xe[4*(q)+1] - mean; \
        float a2 = xe[4*(q)+2] - mean, a3 = xe[4*(q)+3] - mean; \
        v0 = fmaf(a0, a0, v0); v1 = fmaf(a1, a1, v1); \
        v2 = fmaf(a2, a2, v2); v3 = fmaf(a3, a3, v3); \
        xe[4*(q)+0] = a0; xe[4*(q)+1] = a1; xe[4*(q)+2] = a2; xe[4*(q)+3] = a3; }
        REP16(VACE)
        float var  = ((v0 + v1) + (v2 + v3)) * (1.0f / HID);
        float rstd = 1.0f / sqrtf(var + 1e-6f);

        // ---- scale/shift + GELU (formula identical to passing kernel) ----
#define GELE(e, base, LS, LB) { float g = fmaf(xe[(base)+(e)] * rstd, (LS)[(e)], (LB)[(e)]); \
        float g2 = g * g; float g3 = g2 * g; \
        float z  = -1.5957691216057308f * fmaf(0.044715f, g3, g); \
        float ex = __expf(z); \
        xe[(base)+(e)] = __fdividef(g, 1.0f + ex); }
#define GELG(h) { f16s ls, lb2; \
        SLOAD2P(ls, lb2, lns, lnb, (h)*64, (h)*64) \
        AP16(GELE, 16*(h), ls, lb2) }
        REP4(GELG)

        // ---- out matmul [1x64]x[64x7]: flat-ascending == j-ascending per i ----
        float u[SD];
#define IU(i) u[i] = obv[i];
        REP7(IU)
#define OUTE(e, m, W) u[(16*(m)+(e))%7] = fmaf(xe[(16*(m)+(e))/7], (W)[(e)], u[(16*(m)+(e))%7]);
#define OUTG(g) { f16s a0, a1, a2, a3; \
        SLOAD4(a0, a1, a2, a3, ow, (g)*256, (g)*256+64, (g)*256+128, (g)*256+192) \
        AP16(OUTE, 4*(g)+0, a0) AP16(OUTE, 4*(g)+1, a1) \
        AP16(OUTE, 4*(g)+2, a2) AP16(OUTE, 4*(g)+3, a3) }
        REP7(OUTG)

        // ---- L2 normalize ----
        float ss = 0.f;
#define SSQ(i) ss = fmaf(u[i], u[i], ss);
        REP7(SSQ)
        float inv = __fdividef(1.0f, sqrtf(ss) + 1e-8f);

        // ---- damped update + convergence ----
        float dd = 0.f;
#define UPD(i) { float un = u[i] * inv; float mn = 0.5f * mu[i] + 0.5f * un; \
        float d = mn - mu[i]; dd = fmaf(d, d, dd); mu[i] = mn; }
        REP7(UPD)
        if (sqrtf(dd) < 1e-4f) conv = 1.0f;
    }

#define ST(i) out_mu[(size_t)row * SD + (i)] = mu[i];
    REP7(ST)
    out_cv[row] = conv;
}

extern "C" void kernel_launch(void* const* d_in, const int* in_sizes, int n_in,
                              void* d_out, int out_size, void* d_ws, size_t ws_size,
                              hipStream_t stream) {
    const float* s7  = (const float*)d_in[0];
    const float* w0  = (const float*)d_in[1];
    const float* b0  = (const float*)d_in[2];
    const float* lns = (const float*)d_in[3];
    const float* lnb = (const float*)d_in[4];
    const float* ow  = (const float*)d_in[5];
    const float* ob  = (const float*)d_in[6];
    const int Bn = in_sizes[0] / SD;

    float* out_mu = (float*)d_out;
    float* out_cv = out_mu + (size_t)Bn * SD;

    const int block = 256;
    const int grid  = (Bn + block - 1) / block;
    hipLaunchKernelGGL(strange_loop_kernel, dim3(grid), dim3(block), 0, stream,
                       s7, w0, b0, lns, lnb, ow, ob, out_mu, out_cv, Bn);
}